// Round 1
// baseline (192.609 us; speedup 1.0000x reference)
//
#include <hip/hip_runtime.h>
#include <hip/hip_bf16.h>
#include <hip/hip_cooperative_groups.h>

namespace cg = cooperative_groups;

#define T_DIM 1024
#define D_DIM 64
#define WIN   128
#define TILE  128      // output rows per block
#define KROWS 256      // staged rows = TILE + WIN
#define NTHR  512
#define NBLK  256      // 32 (b,h) * 8 tiles

typedef __attribute__((ext_vector_type(8))) short short8;
typedef __attribute__((ext_vector_type(4))) float f32x4;

__device__ __forceinline__ unsigned int pack2bf(float a, float b) {
  unsigned int ua = __float_as_uint(a);
  unsigned int ub = __float_as_uint(b);
  ua = (ua + 0x7fffu + ((ua >> 16) & 1u)) >> 16;   // RNE f32->bf16
  ub = (ub + 0x7fffu + ((ub >> 16) & 1u)) >> 16;
  return ua | (ub << 16);
}

__global__ __launch_bounds__(NTHR, 1)
void gf_kernel(const float* __restrict__ E, float* __restrict__ out,
               float* __restrict__ partials)
{
  // bf16 rows, 8x 16B units per row, unit u stored at (u ^ (r&7)) -> bank-conflict-free frag reads
  __shared__ uint4 Kb4[KROWS * 8];       // 32 KB
  __shared__ float pbuf[32 * 256];       // 32 KB output staging chunk
  __shared__ float ln[KROWS];            // norms
  __shared__ float invden[TILE];         // 1/denom per row
  __shared__ float s_suminv;

  const int tid  = threadIdx.x;
  const int lane = tid & 63;
  const int wv   = tid >> 6;             // 0..7
  const int blk  = blockIdx.x;
  const int bh   = blk >> 3;
  const int base = (blk & 7) * TILE;

  const float* Ebh = E + (size_t)bh * (T_DIM * D_DIM);

  // ---------- stage rows [base-128, base+127] as bf16, swizzled ----------
  #pragma unroll
  for (int it = 0; it < (KROWS * 8) / NTHR; ++it) {
    int u = tid + it * NTHR;
    int r = u >> 3, c = u & 7;           // c = 16B unit (8 bf16 = 8 f32 source)
    int gr = base - WIN + r;
    uint4 w = make_uint4(0u, 0u, 0u, 0u);
    if (gr >= 0) {
      const float4 f0 = *(const float4*)(Ebh + gr * D_DIM + c * 8);
      const float4 f1 = *(const float4*)(Ebh + gr * D_DIM + c * 8 + 4);
      w.x = pack2bf(f0.x, f0.y); w.y = pack2bf(f0.z, f0.w);
      w.z = pack2bf(f1.x, f1.y); w.w = pack2bf(f1.z, f1.w);
    }
    Kb4[(r << 3) + (c ^ (r & 7))] = w;
  }
  __syncthreads();

  // ---------- norms from staged bf16 (wave per row, strided) ----------
  {
    const unsigned short* Kbs = (const unsigned short*)Kb4;
    int u = lane >> 3, e = lane & 7;     // element d = lane
    for (int r = wv; r < KROWS; r += 8) {
      unsigned short bits = Kbs[(((r << 3) + (u ^ (r & 7))) << 3) + e];
      float x = __uint_as_float(((unsigned int)bits) << 16);
      float s = x * x;
      #pragma unroll
      for (int m = 1; m < 64; m <<= 1) s += __shfl_xor(s, m);
      if (lane == 0) ln[r] = sqrtf(s);
    }
  }
  __syncthreads();

  // ---------- MFMA: wave wv computes scores[16 rows][256 cols] ----------
  const short8* KbF = (const short8*)Kb4;
  const int mrow = lane & 15;            // A-row / B-col within tile
  const int kg   = lane >> 4;            // k-group of 8
  f32x4 acc[16];
  {
    int ar = WIN + wv * 16 + mrow;       // LDS row of query
    short8 a0 = KbF[(ar << 3) + (kg ^ (ar & 7))];
    short8 a1 = KbF[(ar << 3) + ((kg + 4) ^ (ar & 7))];
    #pragma unroll
    for (int t = 0; t < 16; ++t) {
      int br = t * 16 + mrow;            // LDS row of key
      short8 b0 = KbF[(br << 3) + (kg ^ (br & 7))];
      short8 b1 = KbF[(br << 3) + ((kg + 4) ^ (br & 7))];
      f32x4 ca = {0.f, 0.f, 0.f, 0.f};
      ca = __builtin_amdgcn_mfma_f32_16x16x32_bf16(a0, b0, ca, 0, 0, 0);
      ca = __builtin_amdgcn_mfma_f32_16x16x32_bf16(a1, b1, ca, 0, 0, 0);
      acc[t] = ca;
    }
  }

  // C layout: col = lane&15 (=mrow), row = kg*4 + g   [m89]
  // local row li = wv*16 + kg*4 + g ; LDS col rj = t*16 + mrow ; j = base-128+rj
  float ni[4], sacc[4] = {0.f, 0.f, 0.f, 0.f};
  #pragma unroll
  for (int g = 0; g < 4; ++g) ni[g] = ln[WIN + wv * 16 + kg * 4 + g];

  #pragma unroll
  for (int t = 0; t < 16; ++t) {
    int rj = t * 16 + mrow;
    float nj = ln[rj];
    #pragma unroll
    for (int g = 0; g < 4; ++g) {
      int li = wv * 16 + kg * 4 + g;
      float cv = acc[t][g] / (ni[g] * nj + 1e-8f);
      acc[t][g] = cv;                    // keep corr in regs
      bool valid = (rj >= li) && (rj <= li + WIN) && (base - WIN + rj >= 0);
      sacc[g] += valid ? cv : 0.f;
    }
  }
  #pragma unroll
  for (int g = 0; g < 4; ++g) {
    float s = sacc[g];
    #pragma unroll
    for (int m = 1; m < 16; m <<= 1) s += __shfl_xor(s, m);
    if (mrow == 0) invden[wv * 16 + kg * 4 + g] = 2048.f / (s + 2048.f);
  }
  __syncthreads();

  // block partial of sum(1/denom) -> ws slot (atomicExch: no zero-init needed)
  if (tid < 64) {
    float v = invden[tid] + invden[tid + 64];
    #pragma unroll
    for (int m = 1; m < 64; m <<= 1) v += __shfl_xor(v, m);
    if (tid == 0) atomicExch(&partials[blk], v);
  }

  cg::this_grid().sync();

  if (tid == 0) {
    float s = 0.f;
    #pragma unroll
    for (int q = 0; q < 8; ++q) s += atomicAdd(&partials[(bh << 3) + q], 0.0f);
    s_suminv = s;
  }
  __syncthreads();

  const float rsum = 1.0f / s_suminv;
  float fit[4], mx[4], esum[4], rinv[4];
  #pragma unroll
  for (int g = 0; g < 4; ++g) {
    fit[g] = invden[wv * 16 + kg * 4 + g] * rsum;  // fitness_i
    mx[g] = -1e30f;
  }

  // v = ((corr+1)/2)*fitness on window, else -inf ; then softmax in-register
  #pragma unroll
  for (int t = 0; t < 16; ++t) {
    int rj = t * 16 + mrow;
    #pragma unroll
    for (int g = 0; g < 4; ++g) {
      int li = wv * 16 + kg * 4 + g;
      bool valid = (rj >= li) && (rj <= li + WIN) && (base - WIN + rj >= 0);
      float v = valid ? (acc[t][g] + 1.0f) * 0.5f * fit[g] : -1e30f;
      acc[t][g] = v;
      mx[g] = fmaxf(mx[g], v);
    }
  }
  #pragma unroll
  for (int g = 0; g < 4; ++g) {
    #pragma unroll
    for (int m = 1; m < 16; m <<= 1) mx[g] = fmaxf(mx[g], __shfl_xor(mx[g], m));
    esum[g] = 0.f;
  }
  #pragma unroll
  for (int t = 0; t < 16; ++t) {
    #pragma unroll
    for (int g = 0; g < 4; ++g) {
      float e = __expf(acc[t][g] - mx[g]);   // masked -> exp(-1e30) = 0
      acc[t][g] = e;
      esum[g] += e;
    }
  }
  #pragma unroll
  for (int g = 0; g < 4; ++g) {
    float s = esum[g];
    #pragma unroll
    for (int m = 1; m < 16; m <<= 1) s += __shfl_xor(s, m);
    rinv[g] = 1.0f / s;
  }

  // ---------- output: 4 chunks of 32 rows, fully coalesced f32x4 stores ----------
  const int rj4base = (base - WIN) / 4;
  for (int cc = 0; cc < 4; ++cc) {
    __syncthreads();
    if ((wv >> 1) == cc) {                 // waves owning rows [cc*32, cc*32+32)
      #pragma unroll
      for (int t = 0; t < 16; ++t) {
        #pragma unroll
        for (int g = 0; g < 4; ++g) {
          int lrow = (wv & 1) * 16 + kg * 4 + g;
          pbuf[lrow * 256 + t * 16 + mrow] = acc[t][g] * rinv[g];
        }
      }
    }
    __syncthreads();
    for (int f = tid; f < 32 * 256; f += NTHR) {
      int lrow = f >> 8, c4 = f & 255;
      int i = base + cc * 32 + lrow;
      int rj4 = c4 - rj4base;
      f32x4 val = {0.f, 0.f, 0.f, 0.f};
      if (rj4 >= 0 && rj4 < 64) val = ((const f32x4*)pbuf)[lrow * 64 + rj4];
      *(f32x4*)(out + ((size_t)bh * T_DIM + i) * T_DIM + (c4 << 2)) = val;
    }
  }
}

extern "C" void kernel_launch(void* const* d_in, const int* in_sizes, int n_in,
                              void* d_out, int out_size, void* d_ws, size_t ws_size,
                              hipStream_t stream) {
  const float* E = (const float*)d_in[0];
  float* out = (float*)d_out;
  float* partials = (float*)d_ws;        // 256 floats used
  void* args[] = { (void*)&E, (void*)&out, (void*)&partials };
  hipLaunchCooperativeKernel((const void*)gf_kernel, dim3(NBLK), dim3(NTHR),
                             args, 0, stream);
}